// Round 1
// baseline (267.958 us; speedup 1.0000x reference)
//
#include <hip/hip_runtime.h>
#include <hip/hip_bf16.h>
#include <math.h>

#define T_TOKENS 8192
#define N_EXP    64
#define CAP      320   // floor(2 * 1.25 * 8192 / 64) = 320, already even, > MIN_CAPACITY

// ---------------------------------------------------------------------------
// Kernel 1: per-token softmax + top-2. One 64-lane wave per token.
// Outputs per token: top1 idx, top2 idx, w1 = probs[top1], w2 = probs[top2].
// ---------------------------------------------------------------------------
__global__ __launch_bounds__(256) void moe_topk_kernel(
    const float* __restrict__ in,
    int* __restrict__ top1, int* __restrict__ top2,
    float* __restrict__ w1, float* __restrict__ w2)
{
    const int token = blockIdx.x * 4 + (threadIdx.x >> 6);
    const int lane  = threadIdx.x & 63;
    if (token >= T_TOKENS) return;

    const float x = in[(size_t)token * N_EXP + lane];

    // --- argmax with first-index tiebreak (matches jnp.argmax) ---
    float v = x; int idx = lane;
    #pragma unroll
    for (int off = 32; off; off >>= 1) {
        float vo = __shfl_xor(v, off);
        int   io = __shfl_xor(idx, off);
        if (vo > v || (vo == v && io < idx)) { v = vo; idx = io; }
    }
    const float m  = v;   // row max (uniform across wave after butterfly)
    const int   i1 = idx;

    // --- softmax denominator ---
    float e = expf(x - m);
    float s = e;
    #pragma unroll
    for (int off = 32; off; off >>= 1) s += __shfl_xor(s, off);

    // --- second argmax (exclude i1) ---
    float v2 = (lane == i1) ? -INFINITY : x;
    int idx2 = lane;
    #pragma unroll
    for (int off = 32; off; off >>= 1) {
        float vo = __shfl_xor(v2, off);
        int   io = __shfl_xor(idx2, off);
        if (vo > v2 || (vo == v2 && io < idx2)) { v2 = vo; idx2 = io; }
    }

    if (lane == 0) {
        top1[token] = i1;
        top2[token] = idx2;
        w1[token]   = 1.0f / s;            // exp(m - m)/s
        w2[token]   = expf(v2 - m) / s;
    }
}

// ---------------------------------------------------------------------------
// Kernel 2: one block per expert. Sequential-chunk ballot scan over the token
// stream reproduces cumsum ranks. rank2 = count1_total + prefix2 (reference
// adds sum(mask1, axis=0) to rank2). Drop at capacity, scatter outputs.
// ---------------------------------------------------------------------------
__global__ __launch_bounds__(256) void moe_rank_scatter_kernel(
    const int* __restrict__ top1, const int* __restrict__ top2,
    const float* __restrict__ w1, const float* __restrict__ w2,
    float* __restrict__ out)
{
    const int e    = blockIdx.x;      // expert id, 0..63
    const int tid  = threadIdx.x;     // 0..255
    const int lane = tid & 63;
    const int wid  = tid >> 6;

    __shared__ int wsum[4];

    float* __restrict__ used = out;
    float* __restrict__ cb   = out + N_EXP;
    float* __restrict__ sec  = out + N_EXP + (size_t)T_TOKENS * N_EXP * CAP;

    const unsigned long long below_mask = (lane == 63)
        ? 0x7FFFFFFFFFFFFFFFull
        : ((1ull << lane) - 1ull);

    int base = 0;

    // ---- pass 1: top1 ranks ----
    for (int t0 = 0; t0 < T_TOKENS; t0 += 256) {
        const int  t     = t0 + tid;
        const bool match = (top1[t] == e);
        const unsigned long long mb = __ballot(match);
        const int below = __popcll(mb & below_mask);
        if (lane == 0) wsum[wid] = __popcll(mb);
        __syncthreads();
        int pre = 0;
        for (int w = 0; w < wid; ++w) pre += wsum[w];
        const int tot = wsum[0] + wsum[1] + wsum[2] + wsum[3];
        if (match) {
            const int r = base + pre + below;
            if (r < CAP) {
                const size_t o = (size_t)t * N_EXP * CAP + (size_t)e * CAP + r;
                cb[o]  = w1[t];
                sec[o] = 1.0f;
            }
        }
        base += tot;
        __syncthreads();
    }
    const int count1 = base;

    // ---- pass 2: top2 ranks (offset by count1) ----
    int base2 = 0;
    for (int t0 = 0; t0 < T_TOKENS; t0 += 256) {
        const int  t     = t0 + tid;
        const bool match = (top2[t] == e);
        const unsigned long long mb = __ballot(match);
        const int below = __popcll(mb & below_mask);
        if (lane == 0) wsum[wid] = __popcll(mb);
        __syncthreads();
        int pre = 0;
        for (int w = 0; w < wid; ++w) pre += wsum[w];
        const int tot = wsum[0] + wsum[1] + wsum[2] + wsum[3];
        if (match) {
            const int r = count1 + base2 + pre + below;
            if (r < CAP) {
                const size_t o = (size_t)t * N_EXP * CAP + (size_t)e * CAP + r;
                cb[o]  = w2[t];
                sec[o] = 1.0f;
            }
        }
        base2 += tot;
        __syncthreads();
    }
    const int count2 = base2;

    if (tid == 0) {
        const int kept1 = min(count1, CAP);
        const int kept2 = min(max(CAP - count1, 0), count2);
        used[e] = (float)(kept1 + kept2);
    }
}

// ---------------------------------------------------------------------------
extern "C" void kernel_launch(void* const* d_in, const int* in_sizes, int n_in,
                              void* d_out, int out_size, void* d_ws, size_t ws_size,
                              hipStream_t stream) {
    const float* in  = (const float*)d_in[0];
    float*       out = (float*)d_out;

    // workspace layout: top1[T] | top2[T] | w1[T] | w2[T]
    int*   top1 = (int*)d_ws;
    int*   top2 = top1 + T_TOKENS;
    float* w1   = (float*)(top2 + T_TOKENS);
    float* w2   = w1 + T_TOKENS;

    // Zero the whole output (poisoned 0xAA before timing; zeros are the
    // default value for used_capacity / cb_weight / sec_mask).
    hipMemsetAsync(d_out, 0, (size_t)out_size * sizeof(float), stream);

    moe_topk_kernel<<<T_TOKENS / 4, 256, 0, stream>>>(in, top1, top2, w1, w2);
    moe_rank_scatter_kernel<<<N_EXP, 256, 0, stream>>>(top1, top2, w1, w2, out);
}